// Round 1
// baseline (1008.614 us; speedup 1.0000x reference)
//
#include <hip/hip_runtime.h>
#include <hip/hip_bf16.h>
#include <math.h>

#define S_LEN 1024
#define HDIM  768
#define NPROC 4
#define VOCAB 50257
#define KSTEPS 4

typedef __attribute__((ext_vector_type(4))) float f32x4;
typedef __attribute__((ext_vector_type(8))) short bf16x8;
typedef __attribute__((ext_vector_type(4))) short short4v;

static __device__ __forceinline__ ushort f2bf(float f) {
  union { __hip_bfloat16 b; ushort u; } cv;
  cv.b = __float2bfloat16(f);
  return cv.u;
}

#define GLOAD16(gp, lp) __builtin_amdgcn_global_load_lds( \
    (const __attribute__((address_space(1))) unsigned int*)(gp), \
    (__attribute__((address_space(3))) unsigned int*)(lp), 16, 0, 0)

// ---------------- f32 -> bf16 convert (weights) ----------------
__global__ void cvt_bf16(const float* __restrict__ in, ushort* __restrict__ out, int n4) {
  const int i = blockIdx.x * 256 + threadIdx.x;
  if (i >= n4) return;
  f32x4 v = ((const f32x4*)in)[i];
  short4v o;
#pragma unroll
  for (int j = 0; j < 4; j++) o[j] = (short)f2bf(v[j]);
  ((short4v*)out)[i] = o;
}

// ---------------- broadcast hidden -> states[p] ----------------
__global__ void init_states(const float* __restrict__ hs, float* __restrict__ st) {
  const int i = blockIdx.x * 256 + threadIdx.x;  // over S*H/4
  f32x4 v = ((const f32x4*)hs)[i];
#pragma unroll
  for (int p = 0; p < NPROC; p++) ((f32x4*)st)[(size_t)p * (S_LEN * HDIM / 4) + i] = v;
}

// ---------------- merge (consensus mix) + LayerNorm -> bf16 ----------------
__global__ __launch_bounds__(256) void merge_ln(
    const float* __restrict__ states, const int* __restrict__ mask,
    const float* __restrict__ alphap, const float* __restrict__ gamma,
    const float* __restrict__ beta, ushort* __restrict__ normed) {
  const int s = blockIdx.x;
  const int tid = threadIdx.x;
  const float mk = (float)mask[s];
  const float al3 = alphap[0] * (1.0f / 3.0f);  // alpha/(P-1)
  float merged[NPROC][3];
  float lsum[NPROC] = {0, 0, 0, 0};
  float lsq[NPROC]  = {0, 0, 0, 0};
#pragma unroll
  for (int e = 0; e < 3; e++) {
    const int h = tid + e * 256;
    float mu[NPROC];
    float sm = 0.f;
#pragma unroll
    for (int p = 0; p < NPROC; p++) {
      mu[p] = states[((size_t)p * S_LEN + s) * HDIM + h] * mk;
      sm += mu[p];
    }
#pragma unroll
    for (int p = 0; p < NPROC; p++) {
      float mg = mu[p] + al3 * (sm - mu[p]);
      merged[p][e] = mg;
      lsum[p] += mg;
      lsq[p]  += mg * mg;
    }
  }
#pragma unroll
  for (int p = 0; p < NPROC; p++) {
#pragma unroll
    for (int off = 32; off > 0; off >>= 1) {
      lsum[p] += __shfl_down(lsum[p], off, 64);
      lsq[p]  += __shfl_down(lsq[p], off, 64);
    }
  }
  __shared__ float rs_[4][NPROC], rq_[4][NPROC];
  const int wv = tid >> 6, ln = tid & 63;
  if (ln == 0) {
#pragma unroll
    for (int p = 0; p < NPROC; p++) { rs_[wv][p] = lsum[p]; rq_[wv][p] = lsq[p]; }
  }
  __syncthreads();
  float mean_[NPROC], rstd[NPROC];
#pragma unroll
  for (int p = 0; p < NPROC; p++) {
    float ts = rs_[0][p] + rs_[1][p] + rs_[2][p] + rs_[3][p];
    float tq = rq_[0][p] + rq_[1][p] + rq_[2][p] + rq_[3][p];
    float mu = ts * (1.f / HDIM);
    float var = tq * (1.f / HDIM) - mu * mu;
    mean_[p] = mu;
    rstd[p] = rsqrtf(var + 1e-5f);
  }
#pragma unroll
  for (int e = 0; e < 3; e++) {
    const int h = tid + e * 256;
    const float gm = gamma[h], bt = beta[h];
#pragma unroll
    for (int p = 0; p < NPROC; p++) {
      float nv = (merged[p][e] - mean_[p]) * rstd[p] * gm + bt;
      normed[((size_t)p * S_LEN + s) * HDIM + h] = f2bf(nv);
    }
  }
}

// ---------------- permute states [p][s][h] -> bf16 rows r = s*4+p ----------------
__global__ void perm_states(const float* __restrict__ st, ushort* __restrict__ out) {
  const int i = blockIdx.x * 256 + threadIdx.x;  // over 4096*768/4
  const int h4 = i % (HDIM / 4);
  const int r = i / (HDIM / 4);
  const int p = r & 3, s = r >> 2;
  f32x4 v = ((const f32x4*)(st + ((size_t)p * S_LEN + s) * HDIM))[h4];
  short4v o;
#pragma unroll
  for (int j = 0; j < 4; j++) o[j] = (short)f2bf(v[j]);
  ((short4v*)(out + (size_t)r * HDIM))[h4] = o;
}

// ---------------- GEMM  C[M,N] = A[M,K] * B[N,K]^T  (bf16 in, f32 acc) ----------------
// MODE 0: +b1, exact GELU, -> bf16 h            (N=768)
// MODE 1: +b2, states = (states*mask + C)*mask  (N=768)
// MODE 2: LM head -> processor_logits + mean -> logits (N=50257, rows r=s*4+p)
template <int MODE>
__global__ __launch_bounds__(256) void gemm_bt(
    const ushort* __restrict__ A, const ushort* __restrict__ B,
    const float* __restrict__ bias, ushort* __restrict__ out_bf,
    float* __restrict__ states, const int* __restrict__ mask,
    float* __restrict__ logits, float* __restrict__ plogits, int nrowsB) {
  __shared__ __align__(16) ushort lA[4096];
  __shared__ __align__(16) ushort lB[4096];
  const int tid = threadIdx.x;
  const int bx = blockIdx.x;
  const int mt = bx & 31;  // M=4096 -> 32 m-tiles
  const int nt = bx >> 5;
  const int wv = tid >> 6, lane = tid & 63;
  const int wm = wv >> 1, wn = wv & 1;
  const int g = lane >> 4, lr = lane & 15;

  f32x4 acc[4][4];
#pragma unroll
  for (int i = 0; i < 4; i++)
#pragma unroll
    for (int j = 0; j < 4; j++) acc[i][j] = (f32x4){0.f, 0.f, 0.f, 0.f};

  const int koff = (tid & 3) * 8;
  const int arow0 = mt * 128 + (tid >> 2);
  const int arow1 = arow0 + 64;
  int brow0 = nt * 128 + (tid >> 2);
  int brow1 = brow0 + 64;
  if (MODE == 2) {
    if (brow0 >= nrowsB) brow0 = nrowsB - 1;
    if (brow1 >= nrowsB) brow1 = nrowsB - 1;
  }
  const ushort* ga0 = A + (size_t)arow0 * HDIM + koff;
  const ushort* ga1 = A + (size_t)arow1 * HDIM + koff;
  const ushort* gb0 = B + (size_t)brow0 * HDIM + koff;
  const ushort* gb1 = B + (size_t)brow1 * HDIM + koff;
  ushort* la0 = lA + wv * 512;
  ushort* la1 = lA + 2048 + wv * 512;
  ushort* lb0 = lB + wv * 512;
  ushort* lb1 = lB + 2048 + wv * 512;

  for (int kt = 0; kt < HDIM / 32; ++kt) {
    GLOAD16(ga0, la0);
    GLOAD16(ga1, la1);
    GLOAD16(gb0, lb0);
    GLOAD16(gb1, lb1);
    ga0 += 32; ga1 += 32; gb0 += 32; gb1 += 32;
    __syncthreads();  // drains vmcnt(0): staged tile visible to all
    bf16x8 af[4], bfr[4];
#pragma unroll
    for (int mi = 0; mi < 4; mi++)
      af[mi] = *(const bf16x8*)(lA + (wm * 64 + mi * 16 + lr) * 32 + g * 8);
#pragma unroll
    for (int ni = 0; ni < 4; ni++)
      bfr[ni] = *(const bf16x8*)(lB + (wn * 64 + ni * 16 + lr) * 32 + g * 8);
#pragma unroll
    for (int mi = 0; mi < 4; mi++)
#pragma unroll
      for (int ni = 0; ni < 4; ni++)
        acc[mi][ni] = __builtin_amdgcn_mfma_f32_16x16x32_bf16(af[mi], bfr[ni], acc[mi][ni], 0, 0, 0);
    __syncthreads();  // all reads done before next stage overwrites LDS
  }

#pragma unroll
  for (int mi = 0; mi < 4; mi++) {
    const int mrow = mt * 128 + wm * 64 + mi * 16 + g * 4;
#pragma unroll
    for (int ni = 0; ni < 4; ni++) {
      const int ncol = nt * 128 + wn * 64 + ni * 16 + lr;
      if (MODE == 0) {
        const float bv = bias[ncol];
#pragma unroll
        for (int j = 0; j < 4; j++) {
          float x = acc[mi][ni][j] + bv;
          float ge = 0.5f * x * (1.f + erff(x * 0.70710678118654752f));
          out_bf[(size_t)(mrow + j) * HDIM + ncol] = f2bf(ge);
        }
      } else if (MODE == 1) {
        const float bv = bias[ncol];
#pragma unroll
        for (int j = 0; j < 4; j++) {
          const int m = mrow + j;
          const int s = m & (S_LEN - 1);
          const float mk = (float)mask[s];
          const size_t idx = (size_t)m * HDIM + ncol;
          const float mut = states[idx] * mk;
          states[idx] = (mut + acc[mi][ni][j] + bv) * mk;
        }
      } else {
        if (ncol < nrowsB) {
          const int s = mrow >> 2;  // rows are r = s*4 + p, mrow % 4 == 0
          const float mean =
              0.25f * (acc[mi][ni][0] + acc[mi][ni][1] + acc[mi][ni][2] + acc[mi][ni][3]);
#pragma unroll
          for (int j = 0; j < 4; j++)
            plogits[((size_t)j * S_LEN + s) * VOCAB + ncol] = acc[mi][ni][j];
          logits[(size_t)s * VOCAB + ncol] = mean;
        }
      }
    }
  }
}

extern "C" void kernel_launch(void* const* d_in, const int* in_sizes, int n_in,
                              void* d_out, int out_size, void* d_ws, size_t ws_size,
                              hipStream_t stream) {
  const float* hidden = (const float*)d_in[0];
  const int*   mask   = (const int*)d_in[1];
  const float* alphap = (const float*)d_in[2];
  const float* gamma  = (const float*)d_in[3];
  const float* beta   = (const float*)d_in[4];
  const float* W1     = (const float*)d_in[5];
  const float* b1     = (const float*)d_in[6];
  const float* W2     = (const float*)d_in[7];
  const float* b2     = (const float*)d_in[8];
  const float* lmw    = (const float*)d_in[9];

  float* logits  = (float*)d_out;
  float* plogits = logits + (size_t)S_LEN * VOCAB;
  float* states  = plogits + (size_t)NPROC * S_LEN * VOCAB;

  uint8_t* ws = (uint8_t*)d_ws;
  ushort* lm_bf  = (ushort*)ws;                       // 77,194,752 B
  ushort* w1_bf  = (ushort*)(ws + 77194752);          // 1,179,648 B
  ushort* w2_bf  = (ushort*)(ws + 78374400);          // 1,179,648 B
  ushort* nrm_bf = (ushort*)(ws + 79554048);          // 6,291,456 B
  ushort* h_bf   = (ushort*)(ws + 85845504);          // 6,291,456 B
  ushort* pm_bf  = (ushort*)(ws + 92136960);          // 6,291,456 B
  if (ws_size < 98428416) return;                     // need ~94 MB scratch

  cvt_bf16<<<(VOCAB * HDIM / 4 + 255) / 256, 256, 0, stream>>>(lmw, lm_bf, VOCAB * HDIM / 4);
  cvt_bf16<<<(HDIM * HDIM / 4 + 255) / 256, 256, 0, stream>>>(W1, w1_bf, HDIM * HDIM / 4);
  cvt_bf16<<<(HDIM * HDIM / 4 + 255) / 256, 256, 0, stream>>>(W2, w2_bf, HDIM * HDIM / 4);
  init_states<<<S_LEN * HDIM / 4 / 256, 256, 0, stream>>>(hidden, states);

  for (int k = 0; k < KSTEPS; k++) {
    merge_ln<<<S_LEN, 256, 0, stream>>>(states, mask, alphap, gamma, beta, nrm_bf);
    gemm_bt<0><<<(HDIM / 128) * 32, 256, 0, stream>>>(nrm_bf, w1_bf, b1, h_bf, nullptr,
                                                      nullptr, nullptr, nullptr, HDIM);
    gemm_bt<1><<<(HDIM / 128) * 32, 256, 0, stream>>>(h_bf, w2_bf, b2, nullptr, states,
                                                      mask, nullptr, nullptr, HDIM);
  }
  perm_states<<<4096 * (HDIM / 4) / 256, 256, 0, stream>>>(states, pm_bf);
  gemm_bt<2><<<((VOCAB + 127) / 128) * 32, 256, 0, stream>>>(
      pm_bf, lm_bf, nullptr, nullptr, nullptr, nullptr, logits, plogits, VOCAB);
}

// Round 2
// 972.894 us; speedup vs baseline: 1.0367x; 1.0367x over previous
//
#include <hip/hip_runtime.h>
#include <hip/hip_bf16.h>
#include <math.h>

#define S_LEN 1024
#define HDIM  768
#define NPROC 4
#define VOCAB 50257
#define KSTEPS 4

typedef __attribute__((ext_vector_type(4))) float f32x4;
typedef __attribute__((ext_vector_type(8))) short bf16x8;
typedef __attribute__((ext_vector_type(4))) short short4v;

static __device__ __forceinline__ ushort f2bf(float f) {
  union { __hip_bfloat16 b; ushort u; } cv;
  cv.b = __float2bfloat16(f);
  return cv.u;
}

#define GLOAD16(gp, lp) __builtin_amdgcn_global_load_lds( \
    (const __attribute__((address_space(1))) unsigned int*)(gp), \
    (__attribute__((address_space(3))) unsigned int*)(lp), 16, 0, 0)

// bijective XCD-aware swizzle (m204 form): contiguous bid chunks per XCD
static __device__ __forceinline__ int xcd_swizzle(int bid, int nwg) {
  const int xcd = bid & 7, local = bid >> 3;
  const int q = nwg >> 3, r = nwg & 7;
  return (xcd < r ? xcd * (q + 1) : r * (q + 1) + (xcd - r) * q) + local;
}

// ---------------- f32 -> bf16 convert (weights) ----------------
__global__ void cvt_bf16(const float* __restrict__ in, ushort* __restrict__ out, int n4) {
  const int i = blockIdx.x * 256 + threadIdx.x;
  if (i >= n4) return;
  f32x4 v = ((const f32x4*)in)[i];
  short4v o;
#pragma unroll
  for (int j = 0; j < 4; j++) o[j] = (short)f2bf(v[j]);
  ((short4v*)out)[i] = o;
}

// ---------------- broadcast hidden -> states[p] ----------------
__global__ void init_states(const float* __restrict__ hs, float* __restrict__ st) {
  const int i = blockIdx.x * 256 + threadIdx.x;  // over S*H/4
  f32x4 v = ((const f32x4*)hs)[i];
#pragma unroll
  for (int p = 0; p < NPROC; p++) ((f32x4*)st)[(size_t)p * (S_LEN * HDIM / 4) + i] = v;
}

// ---------------- merge (consensus mix) + LayerNorm -> bf16 ----------------
__global__ __launch_bounds__(256) void merge_ln(
    const float* __restrict__ states, const int* __restrict__ mask,
    const float* __restrict__ alphap, const float* __restrict__ gamma,
    const float* __restrict__ beta, ushort* __restrict__ normed) {
  const int s = blockIdx.x;
  const int tid = threadIdx.x;
  const float mk = (float)mask[s];
  const float al3 = alphap[0] * (1.0f / 3.0f);  // alpha/(P-1)
  float merged[NPROC][3];
  float lsum[NPROC] = {0, 0, 0, 0};
  float lsq[NPROC]  = {0, 0, 0, 0};
#pragma unroll
  for (int e = 0; e < 3; e++) {
    const int h = tid + e * 256;
    float mu[NPROC];
    float sm = 0.f;
#pragma unroll
    for (int p = 0; p < NPROC; p++) {
      mu[p] = states[((size_t)p * S_LEN + s) * HDIM + h] * mk;
      sm += mu[p];
    }
#pragma unroll
    for (int p = 0; p < NPROC; p++) {
      float mg = mu[p] + al3 * (sm - mu[p]);
      merged[p][e] = mg;
      lsum[p] += mg;
      lsq[p]  += mg * mg;
    }
  }
#pragma unroll
  for (int p = 0; p < NPROC; p++) {
#pragma unroll
    for (int off = 32; off > 0; off >>= 1) {
      lsum[p] += __shfl_down(lsum[p], off, 64);
      lsq[p]  += __shfl_down(lsq[p], off, 64);
    }
  }
  __shared__ float rs_[4][NPROC], rq_[4][NPROC];
  const int wv = tid >> 6, ln = tid & 63;
  if (ln == 0) {
#pragma unroll
    for (int p = 0; p < NPROC; p++) { rs_[wv][p] = lsum[p]; rq_[wv][p] = lsq[p]; }
  }
  __syncthreads();
  float mean_[NPROC], rstd[NPROC];
#pragma unroll
  for (int p = 0; p < NPROC; p++) {
    float ts = rs_[0][p] + rs_[1][p] + rs_[2][p] + rs_[3][p];
    float tq = rq_[0][p] + rq_[1][p] + rq_[2][p] + rq_[3][p];
    float mu = ts * (1.f / HDIM);
    float var = tq * (1.f / HDIM) - mu * mu;
    mean_[p] = mu;
    rstd[p] = rsqrtf(var + 1e-5f);
  }
#pragma unroll
  for (int e = 0; e < 3; e++) {
    const int h = tid + e * 256;
    const float gm = gamma[h], bt = beta[h];
#pragma unroll
    for (int p = 0; p < NPROC; p++) {
      float nv = (merged[p][e] - mean_[p]) * rstd[p] * gm + bt;
      normed[((size_t)p * S_LEN + s) * HDIM + h] = f2bf(nv);
    }
  }
}

// ---------------- permute states [p][s][h] -> bf16 rows r = s*4+p ----------------
__global__ void perm_states(const float* __restrict__ st, ushort* __restrict__ out) {
  const int i = blockIdx.x * 256 + threadIdx.x;  // over 4096*768/4
  const int h4 = i % (HDIM / 4);
  const int r = i / (HDIM / 4);
  const int p = r & 3, s = r >> 2;
  f32x4 v = ((const f32x4*)(st + ((size_t)p * S_LEN + s) * HDIM))[h4];
  short4v o;
#pragma unroll
  for (int j = 0; j < 4; j++) o[j] = (short)f2bf(v[j]);
  ((short4v*)(out + (size_t)r * HDIM))[h4] = o;
}

// ---------------- GEMM  C[M,N] = A[M,K] * B[N,K]^T  (bf16 in, f32 acc) ----------------
// Depth-2 prefetch pipeline: LDS double-buffer, counted vmcnt(4), raw s_barrier.
// MODE 0: +b1, exact GELU, -> bf16 h            (N=768)
// MODE 1: +b2, states = (states*mask + C)*mask  (N=768)
// MODE 2: LM head -> processor_logits + mean -> logits (N=50257, rows r=s*4+p)
template <int MODE>
__global__ __launch_bounds__(256) void gemm_bt(
    const ushort* __restrict__ A, const ushort* __restrict__ B,
    const float* __restrict__ bias, ushort* __restrict__ out_bf,
    float* __restrict__ states, const int* __restrict__ mask,
    float* __restrict__ logits, float* __restrict__ plogits, int nrowsB) {
  __shared__ __align__(16) ushort lsA[2][4096];
  __shared__ __align__(16) ushort lsB[2][4096];
  const int tid = threadIdx.x;
  const int bx = xcd_swizzle(blockIdx.x, gridDim.x);
  const int mt = bx & 31;  // M=4096 -> 32 m-tiles; bid is nt-major -> same-nt on same XCD
  const int nt = bx >> 5;
  const int wv = tid >> 6, lane = tid & 63;
  const int wm = wv >> 1, wn = wv & 1;
  const int g = lane >> 4, lr = lane & 15;

  f32x4 acc[4][4];
#pragma unroll
  for (int i = 0; i < 4; i++)
#pragma unroll
    for (int j = 0; j < 4; j++) acc[i][j] = (f32x4){0.f, 0.f, 0.f, 0.f};

  const int koff = (tid & 3) * 8;
  const int arow0 = mt * 128 + (tid >> 2);
  const int arow1 = arow0 + 64;
  int brow0 = nt * 128 + (tid >> 2);
  int brow1 = brow0 + 64;
  if (MODE == 2) {
    if (brow0 >= nrowsB) brow0 = nrowsB - 1;
    if (brow1 >= nrowsB) brow1 = nrowsB - 1;
  }
  const ushort* gA0 = A + (size_t)arow0 * HDIM + koff;
  const ushort* gA1 = A + (size_t)arow1 * HDIM + koff;
  const ushort* gB0 = B + (size_t)brow0 * HDIM + koff;
  const ushort* gB1 = B + (size_t)brow1 * HDIM + koff;

#define STAGE(kt, buf) do {                          \
    const int o_ = (kt) * 32;                        \
    GLOAD16(gA0 + o_, &lsA[buf][wv * 512]);          \
    GLOAD16(gA1 + o_, &lsA[buf][2048 + wv * 512]);   \
    GLOAD16(gB0 + o_, &lsB[buf][wv * 512]);          \
    GLOAD16(gB1 + o_, &lsB[buf][2048 + wv * 512]);   \
  } while (0)

  constexpr int NT = HDIM / 32;  // 24 k-tiles
  STAGE(0, 0);
  STAGE(1, 1);
  int cur = 0;
  for (int kt = 0; kt < NT; ++kt) {
    // wait for tile kt's 4 loads (tile kt+1's 4 may remain in flight)
    if (kt < NT - 1) {
      asm volatile("s_waitcnt vmcnt(4)" ::: "memory");
    } else {
      asm volatile("s_waitcnt vmcnt(0)" ::: "memory");
    }
    __builtin_amdgcn_s_barrier();          // all waves' tile-kt stages done
    __builtin_amdgcn_sched_barrier(0);
    bf16x8 af[4], bfr[4];
#pragma unroll
    for (int mi = 0; mi < 4; mi++)
      af[mi] = *(const bf16x8*)(&lsA[cur][(wm * 64 + mi * 16 + lr) * 32 + g * 8]);
#pragma unroll
    for (int ni = 0; ni < 4; ni++)
      bfr[ni] = *(const bf16x8*)(&lsB[cur][(wn * 64 + ni * 16 + lr) * 32 + g * 8]);
    asm volatile("s_waitcnt lgkmcnt(0)" ::: "memory");
    __builtin_amdgcn_sched_barrier(0);     // rule #18: keep MFMA below the wait
    __builtin_amdgcn_s_setprio(1);
#pragma unroll
    for (int mi = 0; mi < 4; mi++)
#pragma unroll
      for (int ni = 0; ni < 4; ni++)
        acc[mi][ni] = __builtin_amdgcn_mfma_f32_16x16x32_bf16(af[mi], bfr[ni], acc[mi][ni], 0, 0, 0);
    __builtin_amdgcn_s_setprio(0);
    __builtin_amdgcn_s_barrier();          // all waves' ds_reads of buf[cur] done
    __builtin_amdgcn_sched_barrier(0);
    if (kt + 2 < NT) STAGE(kt + 2, cur);   // overwrite just-consumed buffer
    cur ^= 1;
  }
#undef STAGE

#pragma unroll
  for (int mi = 0; mi < 4; mi++) {
    const int mrow = mt * 128 + wm * 64 + mi * 16 + g * 4;
#pragma unroll
    for (int ni = 0; ni < 4; ni++) {
      const int ncol = nt * 128 + wn * 64 + ni * 16 + lr;
      if (MODE == 0) {
        const float bv = bias[ncol];
#pragma unroll
        for (int j = 0; j < 4; j++) {
          float x = acc[mi][ni][j] + bv;
          float ge = 0.5f * x * (1.f + erff(x * 0.70710678118654752f));
          out_bf[(size_t)(mrow + j) * HDIM + ncol] = f2bf(ge);
        }
      } else if (MODE == 1) {
        const float bv = bias[ncol];
#pragma unroll
        for (int j = 0; j < 4; j++) {
          const int m = mrow + j;
          const int s = m & (S_LEN - 1);
          const float mk = (float)mask[s];
          const size_t idx = (size_t)m * HDIM + ncol;
          const float mut = states[idx] * mk;
          states[idx] = (mut + acc[mi][ni][j] + bv) * mk;
        }
      } else {
        if (ncol < nrowsB) {
          const int s = mrow >> 2;  // rows are r = s*4 + p, mrow % 4 == 0
          const float mean =
              0.25f * (acc[mi][ni][0] + acc[mi][ni][1] + acc[mi][ni][2] + acc[mi][ni][3]);
#pragma unroll
          for (int j = 0; j < 4; j++)
            plogits[((size_t)j * S_LEN + s) * VOCAB + ncol] = acc[mi][ni][j];
          logits[(size_t)s * VOCAB + ncol] = mean;
        }
      }
    }
  }
}

extern "C" void kernel_launch(void* const* d_in, const int* in_sizes, int n_in,
                              void* d_out, int out_size, void* d_ws, size_t ws_size,
                              hipStream_t stream) {
  const float* hidden = (const float*)d_in[0];
  const int*   mask   = (const int*)d_in[1];
  const float* alphap = (const float*)d_in[2];
  const float* gamma  = (const float*)d_in[3];
  const float* beta   = (const float*)d_in[4];
  const float* W1     = (const float*)d_in[5];
  const float* b1     = (const float*)d_in[6];
  const float* W2     = (const float*)d_in[7];
  const float* b2     = (const float*)d_in[8];
  const float* lmw    = (const float*)d_in[9];

  float* logits  = (float*)d_out;
  float* plogits = logits + (size_t)S_LEN * VOCAB;
  float* states  = plogits + (size_t)NPROC * S_LEN * VOCAB;

  uint8_t* ws = (uint8_t*)d_ws;
  ushort* lm_bf  = (ushort*)ws;                       // 77,194,752 B
  ushort* w1_bf  = (ushort*)(ws + 77194752);          // 1,179,648 B
  ushort* w2_bf  = (ushort*)(ws + 78374400);          // 1,179,648 B
  ushort* nrm_bf = (ushort*)(ws + 79554048);          // 6,291,456 B
  ushort* h_bf   = (ushort*)(ws + 85845504);          // 6,291,456 B
  ushort* pm_bf  = (ushort*)(ws + 92136960);          // 6,291,456 B
  if (ws_size < 98428416) return;                     // need ~94 MB scratch

  cvt_bf16<<<(VOCAB * HDIM / 4 + 255) / 256, 256, 0, stream>>>(lmw, lm_bf, VOCAB * HDIM / 4);
  cvt_bf16<<<(HDIM * HDIM / 4 + 255) / 256, 256, 0, stream>>>(W1, w1_bf, HDIM * HDIM / 4);
  cvt_bf16<<<(HDIM * HDIM / 4 + 255) / 256, 256, 0, stream>>>(W2, w2_bf, HDIM * HDIM / 4);
  init_states<<<S_LEN * HDIM / 4 / 256, 256, 0, stream>>>(hidden, states);

  for (int k = 0; k < KSTEPS; k++) {
    merge_ln<<<S_LEN, 256, 0, stream>>>(states, mask, alphap, gamma, beta, nrm_bf);
    gemm_bt<0><<<(HDIM / 128) * 32, 256, 0, stream>>>(nrm_bf, w1_bf, b1, h_bf, nullptr,
                                                      nullptr, nullptr, nullptr, HDIM);
    gemm_bt<1><<<(HDIM / 128) * 32, 256, 0, stream>>>(h_bf, w2_bf, b2, nullptr, states,
                                                      mask, nullptr, nullptr, HDIM);
  }
  perm_states<<<4096 * (HDIM / 4) / 256, 256, 0, stream>>>(states, pm_bf);
  gemm_bt<2><<<((VOCAB + 127) / 128) * 32, 256, 0, stream>>>(
      pm_bf, lm_bf, nullptr, nullptr, nullptr, nullptr, logits, plogits, VOCAB);
}

// Round 4
// 852.583 us; speedup vs baseline: 1.1830x; 1.1411x over previous
//
#include <hip/hip_runtime.h>
#include <hip/hip_bf16.h>
#include <math.h>

#define S_LEN 1024
#define HDIM  768
#define NPROC 4
#define VOCAB 50257
#define KSTEPS 4

typedef __attribute__((ext_vector_type(4))) float f32x4;
typedef __attribute__((ext_vector_type(8))) short bf16x8;
typedef __attribute__((ext_vector_type(4))) short short4v;

static __device__ __forceinline__ ushort f2bf(float f) {
  union { __hip_bfloat16 b; ushort u; } cv;
  cv.b = __float2bfloat16(f);
  return cv.u;
}

#define GLOAD16(gp, lp) __builtin_amdgcn_global_load_lds( \
    (const __attribute__((address_space(1))) unsigned int*)(gp), \
    (__attribute__((address_space(3))) unsigned int*)(lp), 16, 0, 0)

// ---------------- f32 -> bf16 convert (weights) ----------------
__global__ void cvt_bf16(const float* __restrict__ in, ushort* __restrict__ out, int n4) {
  const int i = blockIdx.x * 256 + threadIdx.x;
  if (i >= n4) return;
  f32x4 v = ((const f32x4*)in)[i];
  short4v o;
#pragma unroll
  for (int j = 0; j < 4; j++) o[j] = (short)f2bf(v[j]);
  ((short4v*)out)[i] = o;
}

// ---------------- broadcast hidden -> states[p] ----------------
__global__ void init_states(const float* __restrict__ hs, float* __restrict__ st) {
  const int i = blockIdx.x * 256 + threadIdx.x;  // over S*H/4
  f32x4 v = ((const f32x4*)hs)[i];
#pragma unroll
  for (int p = 0; p < NPROC; p++) ((f32x4*)st)[(size_t)p * (S_LEN * HDIM / 4) + i] = v;
}

// ---------------- merge (consensus mix) + LayerNorm -> bf16 ----------------
__global__ __launch_bounds__(256) void merge_ln(
    const float* __restrict__ states, const int* __restrict__ mask,
    const float* __restrict__ alphap, const float* __restrict__ gamma,
    const float* __restrict__ beta, ushort* __restrict__ normed) {
  const int s = blockIdx.x;
  const int tid = threadIdx.x;
  const float mk = (float)mask[s];
  const float al3 = alphap[0] * (1.0f / 3.0f);  // alpha/(P-1)
  float merged[NPROC][3];
  float lsum[NPROC] = {0, 0, 0, 0};
  float lsq[NPROC]  = {0, 0, 0, 0};
#pragma unroll
  for (int e = 0; e < 3; e++) {
    const int h = tid + e * 256;
    float mu[NPROC];
    float sm = 0.f;
#pragma unroll
    for (int p = 0; p < NPROC; p++) {
      mu[p] = states[((size_t)p * S_LEN + s) * HDIM + h] * mk;
      sm += mu[p];
    }
#pragma unroll
    for (int p = 0; p < NPROC; p++) {
      float mg = mu[p] + al3 * (sm - mu[p]);
      merged[p][e] = mg;
      lsum[p] += mg;
      lsq[p]  += mg * mg;
    }
  }
#pragma unroll
  for (int p = 0; p < NPROC; p++) {
#pragma unroll
    for (int off = 32; off > 0; off >>= 1) {
      lsum[p] += __shfl_down(lsum[p], off, 64);
      lsq[p]  += __shfl_down(lsq[p], off, 64);
    }
  }
  __shared__ float rs_[4][NPROC], rq_[4][NPROC];
  const int wv = tid >> 6, ln = tid & 63;
  if (ln == 0) {
#pragma unroll
    for (int p = 0; p < NPROC; p++) { rs_[wv][p] = lsum[p]; rq_[wv][p] = lsq[p]; }
  }
  __syncthreads();
  float mean_[NPROC], rstd[NPROC];
#pragma unroll
  for (int p = 0; p < NPROC; p++) {
    float ts = rs_[0][p] + rs_[1][p] + rs_[2][p] + rs_[3][p];
    float tq = rq_[0][p] + rq_[1][p] + rq_[2][p] + rq_[3][p];
    float mu = ts * (1.f / HDIM);
    float var = tq * (1.f / HDIM) - mu * mu;
    mean_[p] = mu;
    rstd[p] = rsqrtf(var + 1e-5f);
  }
#pragma unroll
  for (int e = 0; e < 3; e++) {
    const int h = tid + e * 256;
    const float gm = gamma[h], bt = beta[h];
#pragma unroll
    for (int p = 0; p < NPROC; p++) {
      float nv = (merged[p][e] - mean_[p]) * rstd[p] * gm + bt;
      normed[((size_t)p * S_LEN + s) * HDIM + h] = f2bf(nv);
    }
  }
}

// ---------------- permute states [p][s][h] -> bf16 rows r = s*4+p ----------------
__global__ void perm_states(const float* __restrict__ st, ushort* __restrict__ out) {
  const int i = blockIdx.x * 256 + threadIdx.x;  // over 4096*768/4
  const int h4 = i % (HDIM / 4);
  const int r = i / (HDIM / 4);
  const int p = r & 3, s = r >> 2;
  f32x4 v = ((const f32x4*)(st + ((size_t)p * S_LEN + s) * HDIM))[h4];
  short4v o;
#pragma unroll
  for (int j = 0; j < 4; j++) o[j] = (short)f2bf(v[j]);
  ((short4v*)(out + (size_t)r * HDIM))[h4] = o;
}

// ---------------- MLP GEMM  C[M=4096,N=768] = A * B^T, 128x64 tile, BK=32 ----------------
// MODE 0: +b1, exact GELU -> bf16 h ; MODE 1: +b2, states = (states*mask + C)*mask
template <int MODE>
__global__ __launch_bounds__(256, 4) void gemm_mlp(
    const ushort* __restrict__ A, const ushort* __restrict__ B,
    const float* __restrict__ bias, ushort* __restrict__ out_bf,
    float* __restrict__ states, const int* __restrict__ mask) {
  __shared__ __align__(16) ushort lsA[2][4096];  // [128][32]
  __shared__ __align__(16) ushort lsB[2][2048];  // [64][32]
  const int tid = threadIdx.x;
  const int bx = blockIdx.x;
  const int mt = bx & 31;   // bid%8 == mt%8 -> per-XCD A partition (keep!)
  const int nt = bx >> 5;   // 12 n-tiles of 64
  const int wv = tid >> 6, lane = tid & 63;
  const int wm = wv >> 1, wn = wv & 1;
  const int g = lane >> 4, lr = lane & 15;

  f32x4 acc[4][2];
#pragma unroll
  for (int i = 0; i < 4; i++)
#pragma unroll
    for (int j = 0; j < 2; j++) acc[i][j] = (f32x4){0.f, 0.f, 0.f, 0.f};

  const int koff = (tid & 3) * 8;
  const int arow0 = mt * 128 + (tid >> 2);
  const ushort* gA0 = A + (size_t)arow0 * HDIM + koff;
  const ushort* gA1 = gA0 + (size_t)64 * HDIM;
  const ushort* gB0 = B + (size_t)(nt * 64 + (tid >> 2)) * HDIM + koff;
  const int dst = (tid >> 2) * 32 + (tid & 3) * 8;  // ushort offset, row*32 + k8

#define STAGE(kt, buf) do {                      \
    const int o_ = (kt) * 32;                    \
    GLOAD16(gA0 + o_, &lsA[buf][dst]);           \
    GLOAD16(gA1 + o_, &lsA[buf][2048 + dst]);    \
    GLOAD16(gB0 + o_, &lsB[buf][dst]);           \
  } while (0)

  constexpr int NT = HDIM / 32;
  STAGE(0, 0);
  STAGE(1, 1);
  int cur = 0;
  for (int kt = 0; kt < NT; ++kt) {
    if (kt < NT - 1) asm volatile("s_waitcnt vmcnt(3)" ::: "memory");
    else             asm volatile("s_waitcnt vmcnt(0)" ::: "memory");
    __builtin_amdgcn_s_barrier();
    __builtin_amdgcn_sched_barrier(0);
    bf16x8 af[4], bfr[2];
#pragma unroll
    for (int mi = 0; mi < 4; mi++)
      af[mi] = *(const bf16x8*)(&lsA[cur][(wm * 64 + mi * 16 + lr) * 32 + g * 8]);
#pragma unroll
    for (int ni = 0; ni < 2; ni++)
      bfr[ni] = *(const bf16x8*)(&lsB[cur][(wn * 32 + ni * 16 + lr) * 32 + g * 8]);
    asm volatile("s_waitcnt lgkmcnt(0)" ::: "memory");
    __builtin_amdgcn_sched_barrier(0);
    __builtin_amdgcn_s_setprio(1);
#pragma unroll
    for (int mi = 0; mi < 4; mi++)
#pragma unroll
      for (int ni = 0; ni < 2; ni++)
        acc[mi][ni] = __builtin_amdgcn_mfma_f32_16x16x32_bf16(af[mi], bfr[ni], acc[mi][ni], 0, 0, 0);
    __builtin_amdgcn_s_setprio(0);
    __builtin_amdgcn_s_barrier();
    __builtin_amdgcn_sched_barrier(0);
    if (kt + 2 < NT) STAGE(kt + 2, cur);
    cur ^= 1;
  }
#undef STAGE

#pragma unroll
  for (int mi = 0; mi < 4; mi++) {
    const int mrow = mt * 128 + wm * 64 + mi * 16 + g * 4;
#pragma unroll
    for (int ni = 0; ni < 2; ni++) {
      const int ncol = nt * 64 + wn * 32 + ni * 16 + lr;
      const float bv = bias[ncol];
      if (MODE == 0) {
#pragma unroll
        for (int j = 0; j < 4; j++) {
          float x = acc[mi][ni][j] + bv;
          float ge = 0.5f * x * (1.f + erff(x * 0.70710678118654752f));
          out_bf[(size_t)(mrow + j) * HDIM + ncol] = f2bf(ge);
        }
      } else {
#pragma unroll
        for (int j = 0; j < 4; j++) {
          const int m = mrow + j;
          const int s = m & (S_LEN - 1);
          const float mk = (float)mask[s];
          const size_t idx = (size_t)m * HDIM + ncol;
          const float mut = states[idx] * mk;
          states[idx] = (mut + acc[mi][ni][j] + bv) * mk;
        }
      }
    }
  }
}

// ---------------- LM-head GEMM: 256x256 tile, BK=32, 512 thr, 8 waves (2Mx4N) ----------------
// C[4096, 50257] = A[4096,768] * B[50257,768]^T ; rows r = s*4+p.
// Epilogue: LDS-transpose -> 256B-contiguous f32x4 stores of plogits + fused mean -> logits.
__global__ __launch_bounds__(512, 2) void gemm_lm(
    const ushort* __restrict__ A, const ushort* __restrict__ B,
    float* __restrict__ logits, float* __restrict__ plogits, int nrowsB) {
  __shared__ __align__(16) ushort lsA[2][8192];  // [256][32] x 2 = 32 KB
  __shared__ __align__(16) ushort lsB[2][8192];  // 32 KB
  const int tid = threadIdx.x;
  const int bx = blockIdx.x;
  const int mt = bx & 15;   // 16 m-tiles; bid%8 = mt%8 -> per-XCD A partition
  const int nt = bx >> 4;   // 197 n-tiles
  const int wv = tid >> 6, lane = tid & 63;
  const int wm = wv >> 2, wn = wv & 3;
  const int g = lane >> 4, lr = lane & 15;

  f32x4 acc[8][4];
#pragma unroll
  for (int i = 0; i < 8; i++)
#pragma unroll
    for (int j = 0; j < 4; j++) acc[i][j] = (f32x4){0.f, 0.f, 0.f, 0.f};

  const int koff = (tid & 3) * 8;
  const int arow0 = mt * 256 + (tid >> 2);
  int brow0 = nt * 256 + (tid >> 2);
  int brow1 = brow0 + 128;
  if (brow0 >= nrowsB) brow0 = nrowsB - 1;
  if (brow1 >= nrowsB) brow1 = nrowsB - 1;
  const ushort* gA0 = A + (size_t)arow0 * HDIM + koff;
  const ushort* gA1 = gA0 + (size_t)128 * HDIM;
  const ushort* gB0 = B + (size_t)brow0 * HDIM + koff;
  const ushort* gB1 = B + (size_t)brow1 * HDIM + koff;
  const int dst = (tid >> 2) * 32 + (tid & 3) * 8;  // ushort idx: row*32 + k8

#define STAGE(kt, buf) do {                      \
    const int o_ = (kt) * 32;                    \
    GLOAD16(gA0 + o_, &lsA[buf][dst]);           \
    GLOAD16(gA1 + o_, &lsA[buf][4096 + dst]);    \
    GLOAD16(gB0 + o_, &lsB[buf][dst]);           \
    GLOAD16(gB1 + o_, &lsB[buf][4096 + dst]);    \
  } while (0)

  constexpr int NT = HDIM / 32;  // 24
  STAGE(0, 0);
  STAGE(1, 1);
  int cur = 0;
  for (int kt = 0; kt < NT; ++kt) {
    // STAGE = 4 loads/wave; depth-2 => wait current tile's 4, keep next tile's 4 in flight
    if (kt < NT - 1) asm volatile("s_waitcnt vmcnt(4)" ::: "memory");
    else             asm volatile("s_waitcnt vmcnt(0)" ::: "memory");
    __builtin_amdgcn_s_barrier();
    __builtin_amdgcn_sched_barrier(0);
    bf16x8 af[8], bfr[4];
#pragma unroll
    for (int mi = 0; mi < 8; mi++)
      af[mi] = *(const bf16x8*)(&lsA[cur][(wm * 128 + mi * 16 + lr) * 32 + g * 8]);
#pragma unroll
    for (int ni = 0; ni < 4; ni++)
      bfr[ni] = *(const bf16x8*)(&lsB[cur][(wn * 64 + ni * 16 + lr) * 32 + g * 8]);
    asm volatile("s_waitcnt lgkmcnt(0)" ::: "memory");
    __builtin_amdgcn_sched_barrier(0);
    __builtin_amdgcn_s_setprio(1);
#pragma unroll
    for (int mi = 0; mi < 8; mi++)
#pragma unroll
      for (int ni = 0; ni < 4; ni++)
        acc[mi][ni] = __builtin_amdgcn_mfma_f32_16x16x32_bf16(af[mi], bfr[ni], acc[mi][ni], 0, 0, 0);
    __builtin_amdgcn_s_setprio(0);
    __builtin_amdgcn_s_barrier();
    __builtin_amdgcn_sched_barrier(0);
    if (kt + 2 < NT) STAGE(kt + 2, cur);
    cur ^= 1;
  }
#undef STAGE

  // ---- transposed epilogue: per-wave 4 KB f32 scratch in lsA ----
  float* sc = ((float*)&lsA[0][0]) + wv * 1024;  // [16 rows][64 cols]
  const int ncol0 = nt * 256 + wn * 64;
  const bool fast = (ncol0 + 64) <= nrowsB;
#pragma unroll
  for (int mi = 0; mi < 8; mi++) {
    __syncthreads();
#pragma unroll
    for (int ni = 0; ni < 4; ni++)
#pragma unroll
      for (int j = 0; j < 4; j++)
        sc[(g * 4 + j) * 64 + ni * 16 + lr] = acc[mi][ni][j];
    __syncthreads();
    // lane (g,lr): rows g*4+jj (= the 4 p's of s), cols lr*4..+3
    f32x4 v[4];
#pragma unroll
    for (int jj = 0; jj < 4; jj++)
      v[jj] = *(const f32x4*)&sc[(g * 4 + jj) * 64 + lr * 4];
    const f32x4 mean = 0.25f * (v[0] + v[1] + v[2] + v[3]);
    const int s = ((mt * 256 + wm * 128 + mi * 16) >> 2) + g;
    const int c0 = ncol0 + lr * 4;
    if (fast) {
#pragma unroll
      for (int jj = 0; jj < 4; jj++)
        *(f32x4*)&plogits[((size_t)jj * S_LEN + s) * VOCAB + c0] = v[jj];
      *(f32x4*)&logits[(size_t)s * VOCAB + c0] = mean;
    } else {
#pragma unroll
      for (int cc = 0; cc < 4; cc++) {
        if (c0 + cc < nrowsB) {
#pragma unroll
          for (int jj = 0; jj < 4; jj++)
            plogits[((size_t)jj * S_LEN + s) * VOCAB + c0 + cc] = v[jj][cc];
          logits[(size_t)s * VOCAB + c0 + cc] = mean[cc];
        }
      }
    }
  }
}

extern "C" void kernel_launch(void* const* d_in, const int* in_sizes, int n_in,
                              void* d_out, int out_size, void* d_ws, size_t ws_size,
                              hipStream_t stream) {
  const float* hidden = (const float*)d_in[0];
  const int*   mask   = (const int*)d_in[1];
  const float* alphap = (const float*)d_in[2];
  const float* gamma  = (const float*)d_in[3];
  const float* beta   = (const float*)d_in[4];
  const float* W1     = (const float*)d_in[5];
  const float* b1     = (const float*)d_in[6];
  const float* W2     = (const float*)d_in[7];
  const float* b2     = (const float*)d_in[8];
  const float* lmw    = (const float*)d_in[9];

  float* logits  = (float*)d_out;
  float* plogits = logits + (size_t)S_LEN * VOCAB;
  float* states  = plogits + (size_t)NPROC * S_LEN * VOCAB;

  uint8_t* ws = (uint8_t*)d_ws;
  ushort* lm_bf  = (ushort*)ws;                       // 77,194,752 B
  ushort* w1_bf  = (ushort*)(ws + 77194752);          // 1,179,648 B
  ushort* w2_bf  = (ushort*)(ws + 78374400);          // 1,179,648 B
  ushort* nrm_bf = (ushort*)(ws + 79554048);          // 6,291,456 B
  ushort* h_bf   = (ushort*)(ws + 85845504);          // 6,291,456 B
  ushort* pm_bf  = (ushort*)(ws + 92136960);          // 6,291,456 B
  if (ws_size < 98428416) return;                     // need ~94 MB scratch

  cvt_bf16<<<(VOCAB * HDIM / 4 + 255) / 256, 256, 0, stream>>>(lmw, lm_bf, VOCAB * HDIM / 4);
  cvt_bf16<<<(HDIM * HDIM / 4 + 255) / 256, 256, 0, stream>>>(W1, w1_bf, HDIM * HDIM / 4);
  cvt_bf16<<<(HDIM * HDIM / 4 + 255) / 256, 256, 0, stream>>>(W2, w2_bf, HDIM * HDIM / 4);
  init_states<<<S_LEN * HDIM / 4 / 256, 256, 0, stream>>>(hidden, states);

  for (int k = 0; k < KSTEPS; k++) {
    merge_ln<<<S_LEN, 256, 0, stream>>>(states, mask, alphap, gamma, beta, nrm_bf);
    gemm_mlp<0><<<(HDIM / 64) * 32, 256, 0, stream>>>(nrm_bf, w1_bf, b1, h_bf, nullptr, nullptr);
    gemm_mlp<1><<<(HDIM / 64) * 32, 256, 0, stream>>>(h_bf, w2_bf, b2, nullptr, states, mask);
  }
  perm_states<<<4096 * (HDIM / 4) / 256, 256, 0, stream>>>(states, pm_bf);
  gemm_lm<<<((VOCAB + 255) / 256) * 16, 512, 0, stream>>>(pm_bf, lm_bf, logits, plogits, VOCAB);
}